// Round 7
// baseline (39955.325 us; speedup 1.0000x reference)
//
#include <hip/hip_runtime.h>
#include <stdint.h>

// The np reference was generated with XLA-CPU-style FP contraction: the LIF
// recurrence MUST be fmaf(alpha, v, i) — verified bit-exact in round 4's
// designed experiment. All other reductions are robust-margin (order-free).
#pragma clang fp contract(off)

#define BB 128
#define TT 100
#define NN 2048
#define OO 512
#define DLY 10
#define NBLK 321u   // persistent grid size

#define ALPHA_F 0.90483741803595952f
#define DEC_F   0.95122942450071403f
#define OMD_F   0.048770575499285966f
#define A_P 1e-4f
#define A_M 1e-4f
#define THRV 0.02f
#define INVB 0.0078125f   // 1/128 exact

// ---- workspace layout (bytes) ----
// mask region from earlier rounds is dead -> reuse its first bytes for the
// grid-barrier counters (keeps WS_NEED identical to the passing r5 layout).
#define OFF_BAR    ((size_t)0)          // u32 cnt @0, u32 gen @128
#define OFF_HWT    ((size_t)3276800)    // f32 [NN][OO]      hw transposed
#define OFF_IEWT   ((size_t)7471104)    // f32 [OO][OO]      iew transposed, diag-masked
#define OFF_TR1    ((size_t)8519680)    // f32 [BB][NN]
#define OFF_TR2    ((size_t)9568256)    // f32 [BB][OO]
#define OFF_TRI    ((size_t)9830400)    // f32 [BB][OO]
#define OFF_V2     ((size_t)10092544)   // f32 [BB][OO]
#define OFF_VI     ((size_t)10354688)   // f32 [BB][OO]
#define OFF_BUF    ((size_t)10616832)   // f32 [BB][DLY][OO]
#define OFF_EIWD   ((size_t)13238272)   // f32 [OO]          eiw diagonal
#define OFF_ML2    ((size_t)13240320)   // f32 [2][OO]  sum_b l2 (exact ints)
#define OFF_MINH   ((size_t)13244416)   // f32 [2][OO]  sum_b inh
#define OFF_MTR2S  ((size_t)13248512)   // f32 [2][OO]  mean(tr2) state
#define OFF_MTRIS  ((size_t)13252608)   // f32 [2][OO]  mean(tri) state
#define OFF_COLS   ((size_t)13256704)   // f32 [2][OO]  column sums of iewT
#define OFF_FLAGS  ((size_t)13260800)   // u32 [4]: 0=anyL2spike

#define PTRS(ws) \
  float* hwT  = (float*)((ws) + OFF_HWT);  \
  float* iewT = (float*)((ws) + OFF_IEWT); \
  float* tr1  = (float*)((ws) + OFF_TR1);  \
  float* tr2  = (float*)((ws) + OFF_TR2);  \
  float* tri  = (float*)((ws) + OFF_TRI);  \
  float* v2   = (float*)((ws) + OFF_V2);   \
  float* vi   = (float*)((ws) + OFF_VI);   \
  float* buf  = (float*)((ws) + OFF_BUF);  \
  float* eiwd = (float*)((ws) + OFF_EIWD); \
  float* ml2  = (float*)((ws) + OFF_ML2);  \
  float* minh = (float*)((ws) + OFF_MINH); \
  float* m2s  = (float*)((ws) + OFF_MTR2S);\
  float* m3s  = (float*)((ws) + OFF_MTRIS);\
  float* cols = (float*)((ws) + OFF_COLS); \
  unsigned* flags = (unsigned*)((ws) + OFF_FLAGS); \
  unsigned* bar   = (unsigned*)((ws) + OFF_BAR);   \
  (void)hwT;(void)iewT;(void)tr1;(void)tr2;(void)tri;(void)v2;(void)vi; \
  (void)buf;(void)eiwd;(void)ml2;(void)minh;(void)m2s;(void)m3s;(void)cols; \
  (void)flags;(void)bar;

// Device-scope sense barrier (correct across non-coherent per-XCD L2s:
// threadfence = agent-scope acq_rel fence -> L2 writeback/inv; counter ops
// are agent-scope atomics at the coherence point).
__device__ __forceinline__ void gsync(unsigned* cnt, unsigned* gen) {
  __threadfence();
  __syncthreads();
  if (threadIdx.x == 0) {
    unsigned g = __hip_atomic_load(gen, __ATOMIC_RELAXED, __HIP_MEMORY_SCOPE_AGENT);
    unsigned my = __hip_atomic_fetch_add(cnt, 1u, __ATOMIC_ACQ_REL, __HIP_MEMORY_SCOPE_AGENT);
    if (my == NBLK - 1u) {
      __hip_atomic_store(cnt, 0u, __ATOMIC_RELAXED, __HIP_MEMORY_SCOPE_AGENT);
      __hip_atomic_store(gen, g + 1u, __ATOMIC_RELEASE, __HIP_MEMORY_SCOPE_AGENT);
    } else {
      while (__hip_atomic_load(gen, __ATOMIC_ACQUIRE, __HIP_MEMORY_SCOPE_AGENT) == g) {
        __builtin_amdgcn_s_sleep(2);
      }
    }
  }
  __syncthreads();
  __threadfence();
}

// ---------------------------------------------------------------------------
// Kernel A: l1/v1 path (verified FMA recurrence), depth-2 prefetched float4
// stream; no ballots/masks (kLoop rebuilds spike lists from the l1 floats).
// Blocks [0,256): workers. Blocks [256,1280): all workspace init.
// ---------------------------------------------------------------------------
__global__ __launch_bounds__(256) void kA(
    const float* __restrict__ x, const float* __restrict__ w_in,
    const float* __restrict__ hid, const float* __restrict__ eiw_in,
    const float* __restrict__ iew_in, float* __restrict__ out,
    uint8_t* __restrict__ ws)
{
#pragma clang fp contract(off)
  const int bx = blockIdx.x, tid = threadIdx.x;
  PTRS(ws);

  if (bx < 256) {
    const int b = bx >> 1;
    const int half = bx & 1;
    const int n0 = half * 1024 + tid * 4;           // 4 consecutive n per thread
    float wd0 = w_in[(size_t)(n0+0) * NN + (n0+0)];
    float wd1 = w_in[(size_t)(n0+1) * NN + (n0+1)];
    float wd2 = w_in[(size_t)(n0+2) * NN + (n0+2)];
    float wd3 = w_in[(size_t)(n0+3) * NN + (n0+3)];
    const float4* xp4 = (const float4*)(x + ((size_t)b * TT) * NN + n0);
    float4* op4 = (float4*)(out + ((size_t)b * TT) * NN + n0);
    float v0 = 0.f, v1 = 0.f, v2r = 0.f, v3 = 0.f;
    float4 xa = xp4[0];
    float4 xb = xp4[NN/4];
    for (int t = 0; t < TT; ++t) {
      float4 xc = xa;
      xa = xb;
      int tn = t + 2; if (tn > TT - 1) tn = TT - 1;  // clamped prefetch
      xb = xp4[(size_t)tn * (NN/4)];
      v0  = fmaf(ALPHA_F, v0,  wd0 * xc.x);  // bit-exact vs np ref (r4 experiment)
      v1  = fmaf(ALPHA_F, v1,  wd1 * xc.y);
      v2r = fmaf(ALPHA_F, v2r, wd2 * xc.z);
      v3  = fmaf(ALPHA_F, v3,  wd3 * xc.w);
      bool s0 = (v0 > THRV), s1 = (v1 > THRV), s2 = (v2r > THRV), s3 = (v3 > THRV);
      op4[(size_t)t * (NN/4)] = make_float4(s0?1.f:0.f, s1?1.f:0.f, s2?1.f:0.f, s3?1.f:0.f);
      if (s0) v0 = 0.f; if (s1) v1 = 0.f; if (s2) v2r = 0.f; if (s3) v3 = 0.f;
    }
  } else {
    const int idx = (bx - 256) * 256 + tid;         // 0..262143
    #pragma unroll
    for (int k = 0; k < 4; ++k) {                   // hwT[n][q] = hid[q][n]
      int e = idx + k * 262144;
      int n = e & (NN - 1);
      int q = e >> 11;
      hwT[(size_t)n * OO + q] = hid[(size_t)q * NN + n];
    }
    { int p = idx >> 9, q = idx & (OO - 1);         // iewT[p][q] = iew[q][p], diag 0
      iewT[idx] = (p == q) ? 0.f : iew_in[(size_t)q * OO + p]; }
    tr1[idx] = 0.f;
    if (idx < BB * OO) { tr2[idx]=0.f; tri[idx]=0.f; v2[idx]=0.f; vi[idx]=0.f; }
    #pragma unroll
    for (int k = 0; k < 3; ++k) { int e = idx + k * 262144; if (e < BB*DLY*OO) buf[e]=0.f; }
    if (idx < OO) eiwd[idx] = eiw_in[(size_t)idx * OO + idx];
    if (idx < 2*OO) { ml2[idx]=0.f; minh[idx]=0.f; m2s[idx]=0.f; m3s[idx]=0.f; }
    if (idx < OO) {                                 // cols slot0 = masked row-sums of iew_in
      float sacc = 0.f;
      for (int p = 0; p < OO; ++p) if (p != idx) sacc += iew_in[(size_t)idx * OO + p];
      cols[idx] = sacc; cols[OO + idx] = 0.f;
    }
    if (idx < 4) flags[idx] = 0u;
    if (idx == 4) bar[0] = 0u;                      // barrier cnt
    if (idx == 5) bar[32] = 0u;                     // barrier gen (128B apart)
  }
}

// l2 + inh neuron update for one (b,q); byte-identical math to r5/r6.
__device__ __forceinline__ void neuronQ(
    int b, int t, int s, int tm, int q, int train, float l1v, float inh_o,
    float* out, float* v2, float* vi, float* tr2, float* tri, float* buf,
    const float* eiwd, float* ml2, float* minh, unsigned* flags)
{
#pragma clang fp contract(off)
  const int bq = b * OO + q;
  float i2  = l1v - inh_o;
  float v2v = fmaf(ALPHA_F, v2[bq], i2);
  bool l2s = (v2v > THRV);
  v2[bq] = l2s ? 0.f : v2v;
  out[(size_t)BB*TT*NN + ((size_t)b * TT + t) * OO + q] = l2s ? 1.f : 0.f;
  float ii  = l2s ? eiwd[q] : 0.f;
  float viv = fmaf(ALPHA_F, vi[bq], ii);
  bool ih = (viv > THRV);
  vi[bq] = ih ? 0.f : viv;
  buf[((size_t)b * DLY + tm) * OO + q] = ih ? 1.f : 0.f;
  if (train) {
    float d2 = DEC_F * tr2[bq]; tr2[bq] = d2 + OMD_F * (l2s ? 1.f : 0.f);
    float d3 = DEC_F * tri[bq]; tri[bq] = d3 + OMD_F * (ih ? 1.f : 0.f);
    if (l2s) { atomicAdd(&ml2[s * OO + q], 1.f);
               __hip_atomic_store(flags, 1u, __ATOMIC_RELAXED, __HIP_MEMORY_SCOPE_AGENT); }
    if (ih)  { atomicAdd(&minh[s * OO + q], 1.f); }
  }
}

// ---------------------------------------------------------------------------
// kLoop: all 100 steps in ONE persistent kernel (cooperative), 321 blocks:
//  phase A (blocks 0..127): per-batch O-path + fused tr1 update.
//  grid sync.
//  phase B: blocks 0..255 hw tiles, 256..319 iew tiles, 320 eiwd+means.
//  grid sync.
// ---------------------------------------------------------------------------
__global__ __launch_bounds__(256, 2) void kLoop(
    const int* __restrict__ train_p, float* __restrict__ out,
    uint8_t* __restrict__ ws)
{
#pragma clang fp contract(off)
  PTRS(ws);
  const int bx = blockIdx.x, tid = threadIdx.x;
  const int wv = tid >> 6, ln = tid & 63;
  const int train = *train_p;
  unsigned* cnt = &bar[0];
  unsigned* gen = &bar[32];

  __shared__ __align__(16) float s1[BB * 64];
  __shared__ __align__(16) float s2[BB * 64];
  __shared__ unsigned short sidx[NN];
  __shared__ short szer[OO];
  __shared__ unsigned long long sm[32];
  __shared__ unsigned long long zm[8];
  __shared__ int wpre[32];
  __shared__ int zpre[8];
  __shared__ int wtot, ztot;

  for (int t = 0; t < TT; ++t) {
    const int s = t & 1, tm = t % DLY;
    const int se = train ? s : 0;

    // ---------------- phase A ----------------
    if (bx < BB) {
      const int b = bx;
      const float* lp = out + ((size_t)b * TT + t) * NN;
      float lv[8];
      #pragma unroll
      for (int k = 0; k < 8; ++k) {                 // l1 floats -> ballot words
        int n = (k << 8) + tid;
        float v = lp[n];
        lv[k] = v;
        unsigned long long bm = __ballot(v > 0.5f);
        if (ln == 0) sm[(k << 2) + wv] = bm;
      }
      if (train) {                                  // fused tr1 update (sole writer)
        #pragma unroll
        for (int k = 0; k < 8; ++k) {
          int n = (k << 8) + tid;
          float d = DEC_F * tr1[(size_t)b * NN + n];
          tr1[(size_t)b * NN + n] = d + OMD_F * lv[k];
        }
      }
      float bv0 = buf[((size_t)b * DLY + tm) * OO + tid];
      float bv1 = buf[((size_t)b * DLY + tm) * OO + tid + 256];
      float c0 = cols[se * OO + tid];
      float c1 = cols[se * OO + tid + 256];
      { unsigned long long z0 = __ballot(bv0 == 0.f); if (ln == 0) zm[wv] = z0; }
      { unsigned long long z1 = __ballot(bv1 == 0.f); if (ln == 0) zm[4 + wv] = z1; }
      if (train && bx == 0) {                       // cycle double-buffered slots
        cols[(s ^ 1) * OO + tid] = 0.f; cols[(s ^ 1) * OO + tid + 256] = 0.f;
        ml2 [(s ^ 1) * OO + tid] = 0.f; ml2 [(s ^ 1) * OO + tid + 256] = 0.f;
        minh[(s ^ 1) * OO + tid] = 0.f; minh[(s ^ 1) * OO + tid + 256] = 0.f;
      }
      const int anyc = __syncthreads_or((c0 != 0.f || c1 != 0.f) ? 1 : 0);
      if (tid < 32) {                               // scan spike words (wave 0)
        unsigned long long w = sm[tid];
        int pc = __popcll(w), incl = pc;
        #pragma unroll
        for (int d = 1; d < 32; d <<= 1) { int o = __shfl_up(incl, d); if (tid >= d) incl += o; }
        wpre[tid] = incl - pc;
        if (tid == 31) wtot = incl;
      }
      if (tid >= 64 && tid < 72) {                  // scan zero words (wave 1)
        int z = tid - 64;
        unsigned long long w = zm[z];
        int pc = __popcll(w), incl = pc;
        #pragma unroll
        for (int d = 1; d < 8; d <<= 1) { int o = __shfl_up(incl, d); if (z >= d) incl += o; }
        zpre[z] = incl - pc;
        if (z == 7) ztot = incl;
      }
      __syncthreads();
      #pragma unroll
      for (int k = 0; k < 8; ++k) {                 // scatter spike list
        int n = (k << 8) + tid;
        unsigned long long m = sm[n >> 6];
        if ((m >> (n & 63)) & 1ull) {
          int pos = wpre[n >> 6] + __popcll(m & ((1ull << (n & 63)) - 1ull));
          sidx[pos] = (unsigned short)n;
        }
      }
      if (bv0 == 0.f) { int pos = zpre[wv]   + __popcll(zm[wv]   & ((1ull << ln) - 1ull)); szer[pos] = (short)tid; }
      if (bv1 == 0.f) { int pos = zpre[4+wv] + __popcll(zm[4+wv] & ((1ull << ln) - 1ull)); szer[pos] = (short)(tid + 256); }
      __syncthreads();

      float l1v0 = 0.f, l1v1 = 0.f;                 // sparse gather (order-free)
      { const int cnt2 = wtot;
        int k = 0;
        for (; k + 16 <= cnt2; k += 16) {
          #pragma unroll
          for (int u = 0; u < 16; ++u) {
            const float* hp = &hwT[(size_t)sidx[k + u] * OO];
            l1v0 += hp[tid]; l1v1 += hp[tid + 256];
          }
        }
        for (; k < cnt2; ++k) {
          const float* hp = &hwT[(size_t)sidx[k] * OO];
          l1v0 += hp[tid]; l1v1 += hp[tid + 256];
        }
      }
      if (!train) { l1v0 = 0.2f * l1v0; l1v1 = 0.2f * l1v1; }
      float inh0 = 0.f, inh1 = 0.f;                 // complement trick
      if (anyc) {
        float a0 = c0, a1 = c1;
        const int zc = ztot;
        int k = 0;
        for (; k + 8 <= zc; k += 8) {
          #pragma unroll
          for (int u = 0; u < 8; ++u) {
            const float* wp = &iewT[(size_t)szer[k + u] * OO];
            a0 -= wp[tid]; a1 -= wp[tid + 256];
          }
        }
        for (; k < zc; ++k) {
          const float* wp = &iewT[(size_t)szer[k] * OO];
          a0 -= wp[tid]; a1 -= wp[tid + 256];
        }
        inh0 = a0; inh1 = a1;
      }
      neuronQ(b, t, s, tm, tid,       train, l1v0, inh0, out, v2, vi, tr2, tri, buf, eiwd, ml2, minh, flags);
      neuronQ(b, t, s, tm, tid + 256, train, l1v1, inh1, out, v2, vi, tr2, tri, buf, eiwd, ml2, minh, flags);
    }
    gsync(cnt, gen);

    // ---------------- phase B ----------------
    if (train) {
      unsigned any = __hip_atomic_load(&flags[0], __ATOMIC_RELAXED, __HIP_MEMORY_SCOPE_AGENT);
      if (bx < 320) {
        if (any) {
          const bool isHW = (bx < 256);
          const int e  = isHW ? bx : (bx - 256);
          const int pt = e >> 3, qt = e & 7;
          const float* Apre = isHW ? tr1 : tri;
          const int preStride = isHW ? NN : OO;
          #pragma unroll
          for (int it = 0; it < 8; ++it) {          // float4 staging
            int e4 = it * 256 + tid;
            int b = e4 >> 4, i4 = e4 & 15;
            ((float4*)s1)[e4] = *(const float4*)&Apre[(size_t)b * preStride + pt * 64 + i4 * 4];
            ((float4*)s2)[e4] = *(const float4*)&tr2[b * OO + qt * 64 + i4 * 4];
          }
          __syncthreads();
          const int tp = tid >> 4, tq = tid & 15;
          float acc[4][4] = {{0.f,0.f,0.f,0.f},{0.f,0.f,0.f,0.f},{0.f,0.f,0.f,0.f},{0.f,0.f,0.f,0.f}};
          #pragma unroll 4
          for (int b = 0; b < BB; ++b) {
            float4 av = *(const float4*)&s1[b * 64 + tp * 4];
            float4 cv = *(const float4*)&s2[b * 64 + tq * 4];
            acc[0][0] = fmaf(av.x, cv.x, acc[0][0]);
            acc[0][1] = fmaf(av.x, cv.y, acc[0][1]);
            acc[0][2] = fmaf(av.x, cv.z, acc[0][2]);
            acc[0][3] = fmaf(av.x, cv.w, acc[0][3]);
            acc[1][0] = fmaf(av.y, cv.x, acc[1][0]);
            acc[1][1] = fmaf(av.y, cv.y, acc[1][1]);
            acc[1][2] = fmaf(av.y, cv.z, acc[1][2]);
            acc[1][3] = fmaf(av.y, cv.w, acc[1][3]);
            acc[2][0] = fmaf(av.z, cv.x, acc[2][0]);
            acc[2][1] = fmaf(av.z, cv.y, acc[2][1]);
            acc[2][2] = fmaf(av.z, cv.z, acc[2][2]);
            acc[2][3] = fmaf(av.z, cv.w, acc[2][3]);
            acc[3][0] = fmaf(av.w, cv.x, acc[3][0]);
            acc[3][1] = fmaf(av.w, cv.y, acc[3][1]);
            acc[3][2] = fmaf(av.w, cv.z, acc[3][2]);
            acc[3][3] = fmaf(av.w, cv.w, acc[3][3]);
          }
          float mq[4];
          #pragma unroll
          for (int j = 0; j < 4; ++j) {             // exact binary-spike mean recurrence
            int q = qt * 64 + tq * 4 + j;
            mq[j] = DEC_F * m2s[s * OO + q] + OMD_F * (ml2[s * OO + q] * INVB);
          }
          if (isHW) {
            #pragma unroll
            for (int i = 0; i < 4; ++i) {
              size_t p = (size_t)(pt * 64 + tp * 4 + i);
              float4* hp4 = (float4*)&hwT[p * OO + qt * 64 + tq * 4];
              float4 o = *hp4;
              o.x = o.x + (A_P * (acc[i][0] * INVB) - A_M * o.x * mq[0]);
              o.y = o.y + (A_P * (acc[i][1] * INVB) - A_M * o.y * mq[1]);
              o.z = o.z + (A_P * (acc[i][2] * INVB) - A_M * o.z * mq[2]);
              o.w = o.w + (A_P * (acc[i][3] * INVB) - A_M * o.w * mq[3]);
              *hp4 = o;
            }
          } else {
            float csum[4] = {0.f,0.f,0.f,0.f};
            #pragma unroll
            for (int i = 0; i < 4; ++i) {
              int p = pt * 64 + tp * 4 + i;
              float4* wp4 = (float4*)&iewT[(size_t)p * OO + qt * 64 + tq * 4];
              float4 o = *wp4;
              float nv[4];
              #pragma unroll
              for (int j = 0; j < 4; ++j) {
                int q = qt * 64 + tq * 4 + j;
                float old = (&o.x)[j];
                nv[j] = (p == q) ? 0.f
                                 : (old + (A_P * (acc[i][j] * INVB) - A_M * old * mq[j]));
                csum[j] += nv[j];
              }
              *wp4 = make_float4(nv[0], nv[1], nv[2], nv[3]);
            }
            #pragma unroll
            for (int j = 0; j < 4; ++j)
              atomicAdd(&cols[(s ^ 1) * OO + (qt * 64 + tq * 4 + j)], csum[j]);
          }
        }
      } else {
        // block 320: eiw diagonal + mean-state slot cycling (every step)
        for (int k = 0; k < 2; ++k) {
          int q = k * 256 + tid;
          float m2v = DEC_F * m2s[s*OO+q] + OMD_F * (ml2[s*OO+q] * INVB);
          float m3v = DEC_F * m3s[s*OO+q] + OMD_F * (minh[s*OO+q] * INVB);
          m2s[(s^1)*OO+q] = m2v;
          m3s[(s^1)*OO+q] = m3v;
          float hd = 0.f;
          #pragma unroll 4
          for (int b = 0; b < BB; ++b) hd = fmaf(tri[b*OO+q], tr2[b*OO+q], hd);
          hd *= INVB;
          float old = eiwd[q];
          eiwd[q] = old + (A_P * hd - A_M * old * m3v);
        }
      }
    }
    gsync(cnt, gen);
  }
}

extern "C" void kernel_launch(void* const* d_in, const int* in_sizes, int n_in,
                              void* d_out, int out_size, void* d_ws, size_t ws_size,
                              hipStream_t stream) {
  const float* x     = (const float*)d_in[0];
  const float* w_in  = (const float*)d_in[1];
  const float* hid   = (const float*)d_in[2];
  const float* eiw   = (const float*)d_in[3];
  const float* iew   = (const float*)d_in[4];
  const int*   train = (const int*)d_in[5];
  float* out = (float*)d_out;
  uint8_t* ws = (uint8_t*)d_ws;
  (void)in_sizes; (void)n_in; (void)out_size; (void)ws_size;

  hipLaunchKernelGGL(kA, dim3(1280), dim3(256), 0, stream, x, w_in, hid, eiw, iew, out, ws);

  const int* trainp = train; float* outp = out; uint8_t* wsp = ws;
  void* kargs[3] = { (void*)&trainp, (void*)&outp, (void*)&wsp };
  hipError_t err = hipLaunchCooperativeKernel((const void*)kLoop, dim3(NBLK), dim3(256),
                                              kargs, 0, stream);
  if (err != hipSuccess) {
    // Fallback: plain launch. 321 blocks @ ~71KB LDS -> 2 blocks/CU capacity
    // (512 >= 321): all blocks resident from dispatch on an idle device.
    hipLaunchKernelGGL(kLoop, dim3(NBLK), dim3(256), 0, stream, train, out, ws);
  }
}

// Round 8
// 17443.622 us; speedup vs baseline: 2.2905x; 2.2905x over previous
//
#include <hip/hip_runtime.h>
#include <stdint.h>

// The np reference was generated with XLA-CPU-style FP contraction: the LIF
// recurrence MUST be fmaf(alpha, v, i) — verified bit-exact in round 4's
// designed experiment. All other reductions are robust-margin (order-free).
#pragma clang fp contract(off)

#define BB 128
#define TT 100
#define NN 2048
#define OO 512
#define DLY 10
#define NBLK 321u   // persistent grid size

#define ALPHA_F 0.90483741803595952f
#define DEC_F   0.95122942450071403f
#define OMD_F   0.048770575499285966f
#define A_P 1e-4f
#define A_M 1e-4f
#define THRV 0.02f
#define INVB 0.0078125f   // 1/128 exact

// ---- workspace layout (bytes) ----
#define OFF_BAR    ((size_t)0)          // u32 cnt @0, u32 gen @128
#define OFF_HWT    ((size_t)3276800)    // f32 [NN][OO]      hw transposed
#define OFF_IEWT   ((size_t)7471104)    // f32 [OO][OO]      iew transposed, diag-masked
#define OFF_TR1    ((size_t)8519680)    // f32 [BB][NN]
#define OFF_TR2    ((size_t)9568256)    // f32 [BB][OO]
#define OFF_TRI    ((size_t)9830400)    // f32 [BB][OO]
#define OFF_V2     ((size_t)10092544)   // f32 [BB][OO]
#define OFF_VI     ((size_t)10354688)   // f32 [BB][OO]
#define OFF_BUF    ((size_t)10616832)   // f32 [BB][DLY][OO]
#define OFF_EIWD   ((size_t)13238272)   // f32 [OO]          eiw diagonal
#define OFF_ML2    ((size_t)13240320)   // f32 [2][OO]  sum_b l2 (exact ints)
#define OFF_MINH   ((size_t)13244416)   // f32 [2][OO]  sum_b inh
#define OFF_MTR2S  ((size_t)13248512)   // f32 [2][OO]  mean(tr2) state
#define OFF_MTRIS  ((size_t)13252608)   // f32 [2][OO]  mean(tri) state
#define OFF_COLS   ((size_t)13256704)   // f32 [2][OO]  column sums of iewT
#define OFF_FLAGS  ((size_t)13260800)   // u32 [4]: 0=anyL2spike

#define PTRS(ws) \
  float* hwT  = (float*)((ws) + OFF_HWT);  \
  float* iewT = (float*)((ws) + OFF_IEWT); \
  float* tr1  = (float*)((ws) + OFF_TR1);  \
  float* tr2  = (float*)((ws) + OFF_TR2);  \
  float* tri  = (float*)((ws) + OFF_TRI);  \
  float* v2   = (float*)((ws) + OFF_V2);   \
  float* vi   = (float*)((ws) + OFF_VI);   \
  float* buf  = (float*)((ws) + OFF_BUF);  \
  float* eiwd = (float*)((ws) + OFF_EIWD); \
  float* ml2  = (float*)((ws) + OFF_ML2);  \
  float* minh = (float*)((ws) + OFF_MINH); \
  float* m2s  = (float*)((ws) + OFF_MTR2S);\
  float* m3s  = (float*)((ws) + OFF_MTRIS);\
  float* cols = (float*)((ws) + OFF_COLS); \
  unsigned* flags = (unsigned*)((ws) + OFF_FLAGS); \
  unsigned* bar   = (unsigned*)((ws) + OFF_BAR);   \
  (void)hwT;(void)iewT;(void)tr1;(void)tr2;(void)tri;(void)v2;(void)vi; \
  (void)buf;(void)eiwd;(void)ml2;(void)minh;(void)m2s;(void)m3s;(void)cols; \
  (void)flags;(void)bar;

// Device-scope sense barrier. KEY FIX vs r7: the spin uses RELAXED atomic
// loads (sc1 atomics read the coherence point — fresh without any cache
// maintenance). r7's ACQUIRE-in-loop emitted an L2 invalidate per poll,
// which both serialized the barrier AND invalidated working blocks' L2.
// The single release fence (entry) / acquire fence (exit) provide the
// cross-XCD visibility for the bulk data.
__device__ __forceinline__ void gsync(unsigned* cnt, unsigned* gen) {
  __threadfence();                                   // release: wb my L2
  __syncthreads();
  if (threadIdx.x == 0) {
    unsigned g = __hip_atomic_load(gen, __ATOMIC_RELAXED, __HIP_MEMORY_SCOPE_AGENT);
    unsigned my = __hip_atomic_fetch_add(cnt, 1u, __ATOMIC_RELAXED, __HIP_MEMORY_SCOPE_AGENT);
    if (my == NBLK - 1u) {
      __hip_atomic_store(cnt, 0u, __ATOMIC_RELAXED, __HIP_MEMORY_SCOPE_AGENT);
      __hip_atomic_store(gen, g + 1u, __ATOMIC_RELEASE, __HIP_MEMORY_SCOPE_AGENT);
    } else {
      while (__hip_atomic_load(gen, __ATOMIC_RELAXED, __HIP_MEMORY_SCOPE_AGENT) == g) {
        __builtin_amdgcn_s_sleep(4);                 // ~256 cyc backoff, no cache ops
      }
    }
  }
  __syncthreads();
  __threadfence();                                   // acquire: inv so we see others
}

// ---------------------------------------------------------------------------
// Kernel A: l1/v1 path (verified FMA recurrence), depth-2 prefetched float4
// stream. Blocks [0,256): workers. Blocks [256,1280): all workspace init.
// ---------------------------------------------------------------------------
__global__ __launch_bounds__(256) void kA(
    const float* __restrict__ x, const float* __restrict__ w_in,
    const float* __restrict__ hid, const float* __restrict__ eiw_in,
    const float* __restrict__ iew_in, float* __restrict__ out,
    uint8_t* __restrict__ ws)
{
#pragma clang fp contract(off)
  const int bx = blockIdx.x, tid = threadIdx.x;
  PTRS(ws);

  if (bx < 256) {
    const int b = bx >> 1;
    const int half = bx & 1;
    const int n0 = half * 1024 + tid * 4;           // 4 consecutive n per thread
    float wd0 = w_in[(size_t)(n0+0) * NN + (n0+0)];
    float wd1 = w_in[(size_t)(n0+1) * NN + (n0+1)];
    float wd2 = w_in[(size_t)(n0+2) * NN + (n0+2)];
    float wd3 = w_in[(size_t)(n0+3) * NN + (n0+3)];
    const float4* xp4 = (const float4*)(x + ((size_t)b * TT) * NN + n0);
    float4* op4 = (float4*)(out + ((size_t)b * TT) * NN + n0);
    float v0 = 0.f, v1 = 0.f, v2r = 0.f, v3 = 0.f;
    float4 xa = xp4[0];
    float4 xb = xp4[NN/4];
    for (int t = 0; t < TT; ++t) {
      float4 xc = xa;
      xa = xb;
      int tn = t + 2; if (tn > TT - 1) tn = TT - 1;  // clamped prefetch
      xb = xp4[(size_t)tn * (NN/4)];
      v0  = fmaf(ALPHA_F, v0,  wd0 * xc.x);  // bit-exact vs np ref (r4 experiment)
      v1  = fmaf(ALPHA_F, v1,  wd1 * xc.y);
      v2r = fmaf(ALPHA_F, v2r, wd2 * xc.z);
      v3  = fmaf(ALPHA_F, v3,  wd3 * xc.w);
      bool s0 = (v0 > THRV), s1 = (v1 > THRV), s2 = (v2r > THRV), s3 = (v3 > THRV);
      op4[(size_t)t * (NN/4)] = make_float4(s0?1.f:0.f, s1?1.f:0.f, s2?1.f:0.f, s3?1.f:0.f);
      if (s0) v0 = 0.f; if (s1) v1 = 0.f; if (s2) v2r = 0.f; if (s3) v3 = 0.f;
    }
  } else {
    const int idx = (bx - 256) * 256 + tid;         // 0..262143
    #pragma unroll
    for (int k = 0; k < 4; ++k) {                   // hwT[n][q] = hid[q][n]
      int e = idx + k * 262144;
      int n = e & (NN - 1);
      int q = e >> 11;
      hwT[(size_t)n * OO + q] = hid[(size_t)q * NN + n];
    }
    { int p = idx >> 9, q = idx & (OO - 1);         // iewT[p][q] = iew[q][p], diag 0
      iewT[idx] = (p == q) ? 0.f : iew_in[(size_t)q * OO + p]; }
    tr1[idx] = 0.f;
    if (idx < BB * OO) { tr2[idx]=0.f; tri[idx]=0.f; v2[idx]=0.f; vi[idx]=0.f; }
    #pragma unroll
    for (int k = 0; k < 3; ++k) { int e = idx + k * 262144; if (e < BB*DLY*OO) buf[e]=0.f; }
    if (idx < OO) eiwd[idx] = eiw_in[(size_t)idx * OO + idx];
    if (idx < 2*OO) { ml2[idx]=0.f; minh[idx]=0.f; m2s[idx]=0.f; m3s[idx]=0.f; }
    if (idx < OO) {                                 // cols slot0 = masked row-sums of iew_in
      float sacc = 0.f;
      for (int p = 0; p < OO; ++p) if (p != idx) sacc += iew_in[(size_t)idx * OO + p];
      cols[idx] = sacc; cols[OO + idx] = 0.f;
    }
    if (idx < 4) flags[idx] = 0u;
    if (idx == 4) bar[0] = 0u;                      // barrier cnt
    if (idx == 5) bar[32] = 0u;                     // barrier gen (128B apart)
  }
}

// l2 + inh neuron update for one (b,q); byte-identical math to r5/r6.
__device__ __forceinline__ void neuronQ(
    int b, int t, int s, int tm, int q, int train, float l1v, float inh_o,
    float* out, float* v2, float* vi, float* tr2, float* tri, float* buf,
    const float* eiwd, float* ml2, float* minh, unsigned* flags)
{
#pragma clang fp contract(off)
  const int bq = b * OO + q;
  float i2  = l1v - inh_o;
  float v2v = fmaf(ALPHA_F, v2[bq], i2);
  bool l2s = (v2v > THRV);
  v2[bq] = l2s ? 0.f : v2v;
  out[(size_t)BB*TT*NN + ((size_t)b * TT + t) * OO + q] = l2s ? 1.f : 0.f;
  float ii  = l2s ? eiwd[q] : 0.f;
  float viv = fmaf(ALPHA_F, vi[bq], ii);
  bool ih = (viv > THRV);
  vi[bq] = ih ? 0.f : viv;
  buf[((size_t)b * DLY + tm) * OO + q] = ih ? 1.f : 0.f;
  if (train) {
    float d2 = DEC_F * tr2[bq]; tr2[bq] = d2 + OMD_F * (l2s ? 1.f : 0.f);
    float d3 = DEC_F * tri[bq]; tri[bq] = d3 + OMD_F * (ih ? 1.f : 0.f);
    if (l2s) { atomicAdd(&ml2[s * OO + q], 1.f);
               __hip_atomic_store(flags, 1u, __ATOMIC_RELAXED, __HIP_MEMORY_SCOPE_AGENT); }
    if (ih)  { atomicAdd(&minh[s * OO + q], 1.f); }
  }
}

// ---------------------------------------------------------------------------
// kLoop: all 100 steps in ONE persistent kernel (cooperative), 321 blocks:
//  phase A (blocks 0..127): per-batch O-path + fused tr1 update.
//  grid sync (train only; eval is provably sync-free: all state block-local).
//  phase B: blocks 0..255 hw tiles, 256..319 iew tiles, 320 eiwd+means.
//  grid sync.
// ---------------------------------------------------------------------------
__global__ __launch_bounds__(256, 2) void kLoop(
    const int* __restrict__ train_p, float* __restrict__ out,
    uint8_t* __restrict__ ws)
{
#pragma clang fp contract(off)
  PTRS(ws);
  const int bx = blockIdx.x, tid = threadIdx.x;
  const int wv = tid >> 6, ln = tid & 63;
  const int train = *train_p;
  unsigned* cnt = &bar[0];
  unsigned* gen = &bar[32];

  if (!train && bx >= BB) return;   // eval: only phase-A blocks have work

  __shared__ __align__(16) float s1[BB * 64];
  __shared__ __align__(16) float s2[BB * 64];
  __shared__ unsigned short sidx[NN];
  __shared__ short szer[OO];
  __shared__ unsigned long long sm[32];
  __shared__ unsigned long long zm[8];
  __shared__ int wpre[32];
  __shared__ int zpre[8];
  __shared__ int wtot, ztot;

  for (int t = 0; t < TT; ++t) {
    const int s = t & 1, tm = t % DLY;
    const int se = train ? s : 0;

    // ---------------- phase A ----------------
    if (bx < BB) {
      const int b = bx;
      const float* lp = out + ((size_t)b * TT + t) * NN;
      float lv[8];
      #pragma unroll
      for (int k = 0; k < 8; ++k) {                 // l1 floats -> ballot words
        int n = (k << 8) + tid;
        float v = lp[n];
        lv[k] = v;
        unsigned long long bm = __ballot(v > 0.5f);
        if (ln == 0) sm[(k << 2) + wv] = bm;
      }
      if (train) {                                  // fused tr1 update (sole writer)
        #pragma unroll
        for (int k = 0; k < 8; ++k) {
          int n = (k << 8) + tid;
          float d = DEC_F * tr1[(size_t)b * NN + n];
          tr1[(size_t)b * NN + n] = d + OMD_F * lv[k];
        }
      }
      float bv0 = buf[((size_t)b * DLY + tm) * OO + tid];
      float bv1 = buf[((size_t)b * DLY + tm) * OO + tid + 256];
      float c0 = cols[se * OO + tid];
      float c1 = cols[se * OO + tid + 256];
      { unsigned long long z0 = __ballot(bv0 == 0.f); if (ln == 0) zm[wv] = z0; }
      { unsigned long long z1 = __ballot(bv1 == 0.f); if (ln == 0) zm[4 + wv] = z1; }
      if (train && bx == 0) {                       // cycle double-buffered slots
        cols[(s ^ 1) * OO + tid] = 0.f; cols[(s ^ 1) * OO + tid + 256] = 0.f;
        ml2 [(s ^ 1) * OO + tid] = 0.f; ml2 [(s ^ 1) * OO + tid + 256] = 0.f;
        minh[(s ^ 1) * OO + tid] = 0.f; minh[(s ^ 1) * OO + tid + 256] = 0.f;
      }
      const int anyc = __syncthreads_or((c0 != 0.f || c1 != 0.f) ? 1 : 0);
      if (tid < 32) {                               // scan spike words (wave 0)
        unsigned long long w = sm[tid];
        int pc = __popcll(w), incl = pc;
        #pragma unroll
        for (int d = 1; d < 32; d <<= 1) { int o = __shfl_up(incl, d); if (tid >= d) incl += o; }
        wpre[tid] = incl - pc;
        if (tid == 31) wtot = incl;
      }
      if (tid >= 64 && tid < 72) {                  // scan zero words (wave 1)
        int z = tid - 64;
        unsigned long long w = zm[z];
        int pc = __popcll(w), incl = pc;
        #pragma unroll
        for (int d = 1; d < 8; d <<= 1) { int o = __shfl_up(incl, d); if (z >= d) incl += o; }
        zpre[z] = incl - pc;
        if (z == 7) ztot = incl;
      }
      __syncthreads();
      #pragma unroll
      for (int k = 0; k < 8; ++k) {                 // scatter spike list
        int n = (k << 8) + tid;
        unsigned long long m = sm[n >> 6];
        if ((m >> (n & 63)) & 1ull) {
          int pos = wpre[n >> 6] + __popcll(m & ((1ull << (n & 63)) - 1ull));
          sidx[pos] = (unsigned short)n;
        }
      }
      if (bv0 == 0.f) { int pos = zpre[wv]   + __popcll(zm[wv]   & ((1ull << ln) - 1ull)); szer[pos] = (short)tid; }
      if (bv1 == 0.f) { int pos = zpre[4+wv] + __popcll(zm[4+wv] & ((1ull << ln) - 1ull)); szer[pos] = (short)(tid + 256); }
      __syncthreads();

      float l1v0 = 0.f, l1v1 = 0.f;                 // sparse gather (order-free)
      { const int cnt2 = wtot;
        int k = 0;
        for (; k + 16 <= cnt2; k += 16) {
          #pragma unroll
          for (int u = 0; u < 16; ++u) {
            const float* hp = &hwT[(size_t)sidx[k + u] * OO];
            l1v0 += hp[tid]; l1v1 += hp[tid + 256];
          }
        }
        for (; k < cnt2; ++k) {
          const float* hp = &hwT[(size_t)sidx[k] * OO];
          l1v0 += hp[tid]; l1v1 += hp[tid + 256];
        }
      }
      if (!train) { l1v0 = 0.2f * l1v0; l1v1 = 0.2f * l1v1; }
      float inh0 = 0.f, inh1 = 0.f;                 // complement trick
      if (anyc) {
        float a0 = c0, a1 = c1;
        const int zc = ztot;
        int k = 0;
        for (; k + 8 <= zc; k += 8) {
          #pragma unroll
          for (int u = 0; u < 8; ++u) {
            const float* wp = &iewT[(size_t)szer[k + u] * OO];
            a0 -= wp[tid]; a1 -= wp[tid + 256];
          }
        }
        for (; k < zc; ++k) {
          const float* wp = &iewT[(size_t)szer[k] * OO];
          a0 -= wp[tid]; a1 -= wp[tid + 256];
        }
        inh0 = a0; inh1 = a1;
      }
      neuronQ(b, t, s, tm, tid,       train, l1v0, inh0, out, v2, vi, tr2, tri, buf, eiwd, ml2, minh, flags);
      neuronQ(b, t, s, tm, tid + 256, train, l1v1, inh1, out, v2, vi, tr2, tri, buf, eiwd, ml2, minh, flags);
    }
    if (train) gsync(cnt, gen);

    // ---------------- phase B ----------------
    if (train) {
      unsigned any = __hip_atomic_load(&flags[0], __ATOMIC_RELAXED, __HIP_MEMORY_SCOPE_AGENT);
      if (bx < 320) {
        if (any) {
          const bool isHW = (bx < 256);
          const int e  = isHW ? bx : (bx - 256);
          const int pt = e >> 3, qt = e & 7;
          const float* Apre = isHW ? tr1 : tri;
          const int preStride = isHW ? NN : OO;
          #pragma unroll
          for (int it = 0; it < 8; ++it) {          // float4 staging
            int e4 = it * 256 + tid;
            int b = e4 >> 4, i4 = e4 & 15;
            ((float4*)s1)[e4] = *(const float4*)&Apre[(size_t)b * preStride + pt * 64 + i4 * 4];
            ((float4*)s2)[e4] = *(const float4*)&tr2[b * OO + qt * 64 + i4 * 4];
          }
          __syncthreads();
          const int tp = tid >> 4, tq = tid & 15;
          float acc[4][4] = {{0.f,0.f,0.f,0.f},{0.f,0.f,0.f,0.f},{0.f,0.f,0.f,0.f},{0.f,0.f,0.f,0.f}};
          #pragma unroll 4
          for (int b = 0; b < BB; ++b) {
            float4 av = *(const float4*)&s1[b * 64 + tp * 4];
            float4 cv = *(const float4*)&s2[b * 64 + tq * 4];
            acc[0][0] = fmaf(av.x, cv.x, acc[0][0]);
            acc[0][1] = fmaf(av.x, cv.y, acc[0][1]);
            acc[0][2] = fmaf(av.x, cv.z, acc[0][2]);
            acc[0][3] = fmaf(av.x, cv.w, acc[0][3]);
            acc[1][0] = fmaf(av.y, cv.x, acc[1][0]);
            acc[1][1] = fmaf(av.y, cv.y, acc[1][1]);
            acc[1][2] = fmaf(av.y, cv.z, acc[1][2]);
            acc[1][3] = fmaf(av.y, cv.w, acc[1][3]);
            acc[2][0] = fmaf(av.z, cv.x, acc[2][0]);
            acc[2][1] = fmaf(av.z, cv.y, acc[2][1]);
            acc[2][2] = fmaf(av.z, cv.z, acc[2][2]);
            acc[2][3] = fmaf(av.z, cv.w, acc[2][3]);
            acc[3][0] = fmaf(av.w, cv.x, acc[3][0]);
            acc[3][1] = fmaf(av.w, cv.y, acc[3][1]);
            acc[3][2] = fmaf(av.w, cv.z, acc[3][2]);
            acc[3][3] = fmaf(av.w, cv.w, acc[3][3]);
          }
          float mq[4];
          #pragma unroll
          for (int j = 0; j < 4; ++j) {             // exact binary-spike mean recurrence
            int q = qt * 64 + tq * 4 + j;
            mq[j] = DEC_F * m2s[s * OO + q] + OMD_F * (ml2[s * OO + q] * INVB);
          }
          if (isHW) {
            #pragma unroll
            for (int i = 0; i < 4; ++i) {
              size_t p = (size_t)(pt * 64 + tp * 4 + i);
              float4* hp4 = (float4*)&hwT[p * OO + qt * 64 + tq * 4];
              float4 o = *hp4;
              o.x = o.x + (A_P * (acc[i][0] * INVB) - A_M * o.x * mq[0]);
              o.y = o.y + (A_P * (acc[i][1] * INVB) - A_M * o.y * mq[1]);
              o.z = o.z + (A_P * (acc[i][2] * INVB) - A_M * o.z * mq[2]);
              o.w = o.w + (A_P * (acc[i][3] * INVB) - A_M * o.w * mq[3]);
              *hp4 = o;
            }
          } else {
            float csum[4] = {0.f,0.f,0.f,0.f};
            #pragma unroll
            for (int i = 0; i < 4; ++i) {
              int p = pt * 64 + tp * 4 + i;
              float4* wp4 = (float4*)&iewT[(size_t)p * OO + qt * 64 + tq * 4];
              float4 o = *wp4;
              float nv[4];
              #pragma unroll
              for (int j = 0; j < 4; ++j) {
                int q = qt * 64 + tq * 4 + j;
                float old = (&o.x)[j];
                nv[j] = (p == q) ? 0.f
                                 : (old + (A_P * (acc[i][j] * INVB) - A_M * old * mq[j]));
                csum[j] += nv[j];
              }
              *wp4 = make_float4(nv[0], nv[1], nv[2], nv[3]);
            }
            #pragma unroll
            for (int j = 0; j < 4; ++j)
              atomicAdd(&cols[(s ^ 1) * OO + (qt * 64 + tq * 4 + j)], csum[j]);
          }
        }
      } else {
        // block 320: eiw diagonal + mean-state slot cycling (every step)
        for (int k = 0; k < 2; ++k) {
          int q = k * 256 + tid;
          float m2v = DEC_F * m2s[s*OO+q] + OMD_F * (ml2[s*OO+q] * INVB);
          float m3v = DEC_F * m3s[s*OO+q] + OMD_F * (minh[s*OO+q] * INVB);
          m2s[(s^1)*OO+q] = m2v;
          m3s[(s^1)*OO+q] = m3v;
          float hd = 0.f;
          #pragma unroll 4
          for (int b = 0; b < BB; ++b) hd = fmaf(tri[b*OO+q], tr2[b*OO+q], hd);
          hd *= INVB;
          float old = eiwd[q];
          eiwd[q] = old + (A_P * hd - A_M * old * m3v);
        }
      }
      gsync(cnt, gen);
    }
  }
}

extern "C" void kernel_launch(void* const* d_in, const int* in_sizes, int n_in,
                              void* d_out, int out_size, void* d_ws, size_t ws_size,
                              hipStream_t stream) {
  const float* x     = (const float*)d_in[0];
  const float* w_in  = (const float*)d_in[1];
  const float* hid   = (const float*)d_in[2];
  const float* eiw   = (const float*)d_in[3];
  const float* iew   = (const float*)d_in[4];
  const int*   train = (const int*)d_in[5];
  float* out = (float*)d_out;
  uint8_t* ws = (uint8_t*)d_ws;
  (void)in_sizes; (void)n_in; (void)out_size; (void)ws_size;

  hipLaunchKernelGGL(kA, dim3(1280), dim3(256), 0, stream, x, w_in, hid, eiw, iew, out, ws);

  const int* trainp = train; float* outp = out; uint8_t* wsp = ws;
  void* kargs[3] = { (void*)&trainp, (void*)&outp, (void*)&wsp };
  hipError_t err = hipLaunchCooperativeKernel((const void*)kLoop, dim3(NBLK), dim3(256),
                                              kargs, 0, stream);
  if (err != hipSuccess) {
    // Fallback: plain launch. 321 blocks @ ~71KB LDS -> 2 blocks/CU capacity
    // (512 >= 321): all blocks resident from dispatch on an idle device.
    hipLaunchKernelGGL(kLoop, dim3(NBLK), dim3(256), 0, stream, train, out, ws);
  }
}